// Round 4
// baseline (7470.788 us; speedup 1.0000x reference)
//
#include <hip/hip_runtime.h>
#include <hip/hip_bf16.h>
#include <hip/hip_cooperative_groups.h>

namespace cg = cooperative_groups;

// ---- problem dims (fixed) ----
#define NCLS 4
#define BS   16
#define NT   32
#define OC   12
#define HW   4096
#define PIX  65536
#define STATE 786432        // PIX*OC
#define BANK  3145728       // NCLS*STATE
#define NBLK 512            // cooperative grid: 2 blocks/CU worst-case occupancy

typedef short bf16x8 __attribute__((ext_vector_type(8)));
typedef float f32x4  __attribute__((ext_vector_type(4)));

// jax.nn.hard_sigmoid = relu6(x+3)/6
__device__ __forceinline__ float hsig(float v){
    return fminf(fmaxf((v + 3.0f) * (1.0f/6.0f), 0.0f), 1.0f);
}
__device__ __forceinline__ short f2bf(float f){
    union { __hip_bfloat16 h; short s; } u;
    u.h = __float2bfloat16(f);   // RNE
    return u.s;
}

// =====================================================================
// Weight repack (verified R2): fragment-order bf16.
// wgt[cell][tap][kb][nt][lane], elem j = B[k=kb*32+(lane>>4)*8+j][n=nt*16+(lane&15)]
// =====================================================================
__global__ __launch_bounds__(256) void repack_kernel(
    const float* __restrict__ Wxg, const float* __restrict__ Whg,
    const float* __restrict__ Wxc, const float* __restrict__ Whc,
    bf16x8* __restrict__ wgt)
{
    int id = blockIdx.x * 256 + threadIdx.x;    // < 6912
    if (id >= 6912) return;
    int cell = id / 3456;
    int rem  = id - cell * 3456;
    int tap  = rem / 384;  rem -= tap * 384;
    int kb   = rem / 192;  rem -= kb * 192;
    int nt   = rem / 64;
    int lane = rem - nt * 64;
    int quad = lane >> 4;
    int n    = nt * 16 + (lane & 15);
    union { bf16x8 v; short s[8]; } o;
    #pragma unroll
    for (int j = 0; j < 8; ++j){
        int k = kb * 32 + quad * 8 + j;
        float f = 0.0f;
        if (cell == 0){
            if (k < 48)      f = Wxg[(tap*48 + k)*48 + n];
            else if (k < 60) f = Whg[(tap*12 + (k-48))*48 + n];
        } else {
            if (k < 24)      f = Wxc[(tap*24 + k)*48 + n];
            else if (k < 36) f = Whc[(tap*12 + (k-24))*48 + n];
        }
        o.s[j] = f2bf(f);
    }
    wgt[id] = o.v;
}

// x (fp32) -> bf16, once.
__global__ __launch_bounds__(256) void convert_kernel(
    const float* __restrict__ x, short* __restrict__ xbf)
{
    int i = blockIdx.x * 256 + threadIdx.x;
    const float4* xf = (const float4*)x;
    float4 a = xf[i*2], b = xf[i*2 + 1];
    union { bf16x8 v; short s[8]; } o;
    o.s[0]=f2bf(a.x); o.s[1]=f2bf(a.y); o.s[2]=f2bf(a.z); o.s[3]=f2bf(a.w);
    o.s[4]=f2bf(b.x); o.s[5]=f2bf(b.y); o.s[6]=f2bf(b.z); o.s[7]=f2bf(b.w);
    ((bf16x8*)xbf)[i] = o.v;
}

// LDS halo: plane-major  halo[q8][r][c][8ch] bf16, r in [0,3), c in [0,66)
#define HALO_SHORTS (8*198*8)     // 25344 B

// =====================================================================
// Persistent cooperative kernel, 512 blocks; block handles rows
// rb = blockIdx.x + d*512 for d in {0,1} (compile-time unrolled so all
// per-row recurrent state stays in registers). 2 grid syncs/step.
// Bank slot cid_prev is stale during gen staging: blocks with
// b>>2==cid_prev read htmp_prev (flat slot content) instead and write
// their own rows back to bank (block-uniform branch).
// =====================================================================
__global__ __launch_bounds__(256, 4) void lstm_kernel(
    short* __restrict__ bank,          // (PIX*48) bf16 flat = class_h raw view
    short* __restrict__ genh0, short* __restrict__ genh1,   // (PIX,12) bf16
    short* __restrict__ htmp0, short* __restrict__ htmp1,   // (PIX,12) bf16
    const short* __restrict__ xbf,     // (BS,NT,HW,12) bf16
    const int* __restrict__ ids,
    const bf16x8* __restrict__ wgt_gen,
    const bf16x8* __restrict__ wgt_cls,
    const float* __restrict__ bias_g,
    const float* __restrict__ bias_c,
    float* __restrict__ out)           // (PIX,12) f32
{
    cg::grid_group grid = cg::this_grid();
    __shared__ __align__(16) short halo[HALO_SHORTS];

    const int tid  = threadIdx.x;
    const int lane = tid & 63;
    const int w    = tid >> 6;
    const int m    = lane & 15;
    const int quad = lane >> 4;
    const int colbase = 16*w + m;

    // register-resident recurrent state, [d][s], idx = lane*3+s
    float genc[2][3] = {{0.f,0.f,0.f},{0.f,0.f,0.f}};
    float cs0[2][3]  = {{0.f,0.f,0.f},{0.f,0.f,0.f}};
    float cs1[2][3]  = {{0.f,0.f,0.f},{0.f,0.f,0.f}};
    float cs2[2][3]  = {{0.f,0.f,0.f},{0.f,0.f,0.f}};
    float cs3[2][3]  = {{0.f,0.f,0.f},{0.f,0.f,0.f}};
    float oacc[2][3] = {{0.f,0.f,0.f},{0.f,0.f,0.f}};
    int cid_prev = -1;

    for (int t = 0; t < NT; ++t){
        short* hin       = (t & 1) ? genh1 : genh0;
        short* hnew      = (t & 1) ? genh0 : genh1;
        short* htmp_prev = (t & 1) ? htmp0 : htmp1;
        short* htmp_new  = (t & 1) ? htmp1 : htmp0;

        // ================= phase G (general cell) =================
        #pragma unroll
        for (int d = 0; d < 2; ++d){
            const int rb = blockIdx.x + d*NBLK;
            const int p0 = rb << 6;
            const int b  = rb >> 6;
            const int y  = rb & 63;
            const bool slotmatch = (cid_prev >= 0) && ((b >> 2) == cid_prev);
            const short* bsrc = slotmatch ? htmp_prev : bank;
            for (int tk = tid; tk < 1584; tk += 256){
                int rc = tk >> 3, q8 = tk & 7;
                int r  = rc / 66, c = rc - r * 66;
                int yy = y + r - 1, xx = c - 1;
                bool valid = (yy >= 0) & (yy < 64) & (xx >= 0) & (xx < 64);
                int p  = (b << 12) + (yy << 6) + xx;
                int pb = slotmatch ? (p & 16383) : p;
                union { bf16x8 v; uint2 u2[2]; uint4 u4; } ch;
                ch.u4 = make_uint4(0u, 0u, 0u, 0u);
                if (valid){
                    if (q8 < 6){
                        ch.u4 = *(const uint4*)(bsrc + pb*48 + q8*8);
                        if (slotmatch && r == 1)            // own row: refresh bank
                            *(uint4*)(bank + p*48 + q8*8) = ch.u4;
                    } else if (q8 == 6){
                        ch.u2[0] = *(const uint2*)(hin + p*12);
                        ch.u2[1] = *(const uint2*)(hin + p*12 + 4);
                    } else {
                        ch.u2[0] = *(const uint2*)(hin + p*12 + 8);
                    }
                }
                *(bf16x8*)&halo[(q8*198 + rc)*8] = ch.v;
            }
            __syncthreads();

            f32x4 acc0 = {0.f,0.f,0.f,0.f};
            f32x4 acc1 = acc0, acc2 = acc0;
            #pragma unroll
            for (int ky = 0; ky < 3; ++ky){
                #pragma unroll
                for (int kx = 0; kx < 3; ++kx){
                    const int tap = ky*3 + kx;
                    #pragma unroll
                    for (int kb = 0; kb < 2; ++kb){
                        const bf16x8 a = *(const bf16x8*)
                            &halo[(((kb*4 + quad)*198) + ky*66 + colbase + kx)*8];
                        const bf16x8* wp = wgt_gen + ((tap*2 + kb)*3)*64 + lane;
                        acc0 = __builtin_amdgcn_mfma_f32_16x16x32_bf16(a, wp[0],   acc0, 0,0,0);
                        acc1 = __builtin_amdgcn_mfma_f32_16x16x32_bf16(a, wp[64],  acc1, 0,0,0);
                        acc2 = __builtin_amdgcn_mfma_f32_16x16x32_bf16(a, wp[128], acc2, 0,0,0);
                    }
                }
            }

            __syncthreads();
            float* zw = ((float*)halo) + w * 768;
            #pragma unroll
            for (int r = 0; r < 4; ++r){
                zw[(quad*4 + r)*48 +      m] = acc0[r];
                zw[(quad*4 + r)*48 + 16 + m] = acc1[r];
                zw[(quad*4 + r)*48 + 32 + m] = acc2[r];
            }
            __syncthreads();
            const int pbase = p0 + 16*w;
            #pragma unroll
            for (int s = 0; s < 3; ++s){
                int idx = lane*3 + s;
                int px  = idx / 12;
                int j   = idx - px*12;
                float zi = zw[px*48 +      j] + bias_g[j];
                float zf = zw[px*48 + 12 + j] + bias_g[12 + j];
                float zg = zw[px*48 + 24 + j] + bias_g[24 + j];
                float zo = zw[px*48 + 36 + j] + bias_g[36 + j];
                float cn = hsig(zf)*genc[d][s] + hsig(zi)*tanhf(zg);
                genc[d][s] = cn;
                hnew[pbase*12 + idx] = f2bf(hsig(zo)*tanhf(cn));
            }
            __syncthreads();   // zw reads done before next-row staging
        }
        grid.sync();

        // ================= phase C (class cell) =================
        const int cid = ids[t];
        #pragma unroll
        for (int d = 0; d < 2; ++d){
            const int rb = blockIdx.x + d*NBLK;
            const int p0 = rb << 6;
            const int b  = rb >> 6;
            const int y  = rb & 63;
            const short* chs   = bank + (size_t)cid * STATE;        // fresh
            const short* frame = xbf + (size_t)(b*NT + t) * (HW*12);
            for (int tk = tid; tk < 1584; tk += 256){
                int rc = tk >> 3, q8 = tk & 7;
                int r  = rc / 66, c = rc - r * 66;
                int yy = y + r - 1, xx = c - 1;
                bool valid = (yy >= 0) & (yy < 64) & (xx >= 0) & (xx < 64);
                int pl = (yy << 6) + xx;
                int p  = (b << 12) + pl;
                union { bf16x8 v; uint2 u2[2]; uint4 u4; } ch;
                ch.u4 = make_uint4(0u, 0u, 0u, 0u);
                if (valid){
                    if (q8 == 0){                      // frame ch 0..7
                        ch.u2[0] = *(const uint2*)(frame + pl*12);
                        ch.u2[1] = *(const uint2*)(frame + pl*12 + 4);
                    } else if (q8 == 1){               // frame 8..11 | gen_h 0..3
                        ch.u2[0] = *(const uint2*)(frame + pl*12 + 8);
                        ch.u2[1] = *(const uint2*)(hnew + p*12);
                    } else if (q8 == 2){               // gen_h 4..11
                        ch.u2[0] = *(const uint2*)(hnew + p*12 + 4);
                        ch.u2[1] = *(const uint2*)(hnew + p*12 + 8);
                    } else if (q8 == 3){               // class_h 0..7
                        ch.u2[0] = *(const uint2*)(chs + p*12);
                        ch.u2[1] = *(const uint2*)(chs + p*12 + 4);
                    } else if (q8 == 4){               // class_h 8..11 + pad
                        ch.u2[0] = *(const uint2*)(chs + p*12 + 8);
                    }
                }
                *(bf16x8*)&halo[(q8*198 + rc)*8] = ch.v;
            }
            __syncthreads();

            f32x4 acc0 = {0.f,0.f,0.f,0.f};
            f32x4 acc1 = acc0, acc2 = acc0;
            #pragma unroll
            for (int ky = 0; ky < 3; ++ky){
                #pragma unroll
                for (int kx = 0; kx < 3; ++kx){
                    const int tap = ky*3 + kx;
                    #pragma unroll
                    for (int kb = 0; kb < 2; ++kb){
                        const bf16x8 a = *(const bf16x8*)
                            &halo[(((kb*4 + quad)*198) + ky*66 + colbase + kx)*8];
                        const bf16x8* wp = wgt_cls + ((tap*2 + kb)*3)*64 + lane;
                        acc0 = __builtin_amdgcn_mfma_f32_16x16x32_bf16(a, wp[0],   acc0, 0,0,0);
                        acc1 = __builtin_amdgcn_mfma_f32_16x16x32_bf16(a, wp[64],  acc1, 0,0,0);
                        acc2 = __builtin_amdgcn_mfma_f32_16x16x32_bf16(a, wp[128], acc2, 0,0,0);
                    }
                }
            }

            __syncthreads();
            float* zw = ((float*)halo) + w * 768;
            #pragma unroll
            for (int r = 0; r < 4; ++r){
                zw[(quad*4 + r)*48 +      m] = acc0[r];
                zw[(quad*4 + r)*48 + 16 + m] = acc1[r];
                zw[(quad*4 + r)*48 + 32 + m] = acc2[r];
            }
            __syncthreads();
            const int pbase = p0 + 16*w;
            #pragma unroll
            for (int s = 0; s < 3; ++s){
                int idx = lane*3 + s;
                int px  = idx / 12;
                int j   = idx - px*12;
                float zi = zw[px*48 +      j] + bias_c[j];
                float zf = zw[px*48 + 12 + j] + bias_c[12 + j];
                float zg = zw[px*48 + 24 + j] + bias_c[24 + j];
                float zo = zw[px*48 + 36 + j] + bias_c[36 + j];
                float cold;
                if      (cid == 0) cold = cs0[d][s];
                else if (cid == 1) cold = cs1[d][s];
                else if (cid == 2) cold = cs2[d][s];
                else               cold = cs3[d][s];
                float cn = hsig(zf)*cold + hsig(zi)*tanhf(zg);
                if      (cid == 0) cs0[d][s] = cn;
                else if (cid == 1) cs1[d][s] = cn;
                else if (cid == 2) cs2[d][s] = cn;
                else               cs3[d][s] = cn;
                float h = hsig(zo)*tanhf(cn);
                htmp_new[pbase*12 + idx] = f2bf(h);
                oacc[d][s] += h;
            }
            __syncthreads();
        }
        cid_prev = cid;
        grid.sync();
    }

    #pragma unroll
    for (int d = 0; d < 2; ++d){
        const int pbase = ((blockIdx.x + d*NBLK) << 6) + 16*w;
        #pragma unroll
        for (int s = 0; s < 3; ++s)
            out[pbase*12 + lane*3 + s] = oacc[d][s];
    }
}

extern "C" void kernel_launch(void* const* d_in, const int* in_sizes, int n_in,
                              void* d_out, int out_size, void* d_ws, size_t ws_size,
                              hipStream_t stream)
{
    (void)in_sizes; (void)n_in; (void)out_size; (void)ws_size;
    const float* x    = (const float*)d_in[0];
    const int*   ids  = (const int*)  d_in[1];
    const float* Wxg  = (const float*)d_in[2];
    const float* Whg  = (const float*)d_in[3];
    const float* bg   = (const float*)d_in[4];
    const float* Wxc  = (const float*)d_in[5];
    const float* Whc  = (const float*)d_in[6];
    const float* bc   = (const float*)d_in[7];
    float* out = (float*)d_out;

    char* base = (char*)d_ws;
    short*  bank   = (short*) (base);               // 6,291,456 B
    short*  genh0  = (short*) (base + 6291456);     // 1,572,864
    short*  genh1  = (short*) (base + 7864320);     // 1,572,864
    short*  htmp0  = (short*) (base + 9437184);     // 1,572,864
    short*  htmp1  = (short*) (base + 11010048);    // 1,572,864
    short*  xbf    = (short*) (base + 12582912);    // 50,331,648
    bf16x8* wgt    = (bf16x8*)(base + 62914560);    // 110,592
    const bf16x8* wgt_gen = wgt;
    const bf16x8* wgt_cls = wgt + 3456;

    hipMemsetAsync(bank,  0, (size_t)2*BANK,  stream);
    hipMemsetAsync(genh0, 0, (size_t)2*STATE, stream);

    repack_kernel<<<27, 256, 0, stream>>>(Wxg, Whg, Wxc, Whc, wgt);
    convert_kernel<<<12288, 256, 0, stream>>>(x, xbf);

    void* args[] = { &bank, &genh0, &genh1, &htmp0, &htmp1, (void*)&xbf,
                     (void*)&ids, (void*)&wgt_gen, (void*)&wgt_cls,
                     (void*)&bg, (void*)&bc, &out };
    hipLaunchCooperativeKernel((void*)lstm_kernel, dim3(NBLK), dim3(256),
                               args, 0, stream);
}

// Round 5
// 1233.164 us; speedup vs baseline: 6.0582x; 6.0582x over previous
//
#include <hip/hip_runtime.h>
#include <hip/hip_bf16.h>

// ---- problem dims (fixed) ----
#define NCLS 4
#define BS   16
#define NT   32
#define OC   12
#define HW   4096
#define PIX  65536
#define STATE 786432        // PIX*OC
#define BANK  3145728       // NCLS*STATE

typedef short bf16x8 __attribute__((ext_vector_type(8)));
typedef float f32x4  __attribute__((ext_vector_type(4)));

// jax.nn.hard_sigmoid = relu6(x+3)/6
__device__ __forceinline__ float hsig(float v){
    return fminf(fmaxf((v + 3.0f) * (1.0f/6.0f), 0.0f), 1.0f);
}
__device__ __forceinline__ short f2bf(float f){
    union { __hip_bfloat16 h; short s; } u;
    u.h = __float2bfloat16(f);   // RNE
    return u.s;
}

// =====================================================================
// Weight repack (verified R2): fragment-order bf16.
// wgt[cell][tap][kb][nt][lane], elem j = B[k=kb*32+(lane>>4)*8+j][n=nt*16+(lane&15)]
// =====================================================================
__global__ __launch_bounds__(256) void repack_kernel(
    const float* __restrict__ Wxg, const float* __restrict__ Whg,
    const float* __restrict__ Wxc, const float* __restrict__ Whc,
    bf16x8* __restrict__ wgt)
{
    int id = blockIdx.x * 256 + threadIdx.x;    // < 6912
    if (id >= 6912) return;
    int cell = id / 3456;
    int rem  = id - cell * 3456;
    int tap  = rem / 384;  rem -= tap * 384;
    int kb   = rem / 192;  rem -= kb * 192;
    int nt   = rem / 64;
    int lane = rem - nt * 64;
    int quad = lane >> 4;
    int n    = nt * 16 + (lane & 15);
    union { bf16x8 v; short s[8]; } o;
    #pragma unroll
    for (int j = 0; j < 8; ++j){
        int k = kb * 32 + quad * 8 + j;
        float f = 0.0f;
        if (cell == 0){
            if (k < 48)      f = Wxg[(tap*48 + k)*48 + n];
            else if (k < 60) f = Whg[(tap*12 + (k-48))*48 + n];
        } else {
            if (k < 24)      f = Wxc[(tap*24 + k)*48 + n];
            else if (k < 36) f = Whc[(tap*12 + (k-24))*48 + n];
        }
        o.s[j] = f2bf(f);
    }
    wgt[id] = o.v;
}

// x (fp32) -> bf16, once.
__global__ __launch_bounds__(256) void convert_kernel(
    const float* __restrict__ x, short* __restrict__ xbf)
{
    int i = blockIdx.x * 256 + threadIdx.x;
    const float4* xf = (const float4*)x;
    float4 a = xf[i*2], b = xf[i*2 + 1];
    union { bf16x8 v; short s[8]; } o;
    o.s[0]=f2bf(a.x); o.s[1]=f2bf(a.y); o.s[2]=f2bf(a.z); o.s[3]=f2bf(a.w);
    o.s[4]=f2bf(b.x); o.s[5]=f2bf(b.y); o.s[6]=f2bf(b.z); o.s[7]=f2bf(b.w);
    ((bf16x8*)xbf)[i] = o.v;
}

// LDS halo: plane-major  halo[q8][r][c][8ch] bf16, r in [0,3), c in [0,66)
#define HALO_SHORTS (8*198*8)     // 25344 B

// XCD-aware row swizzle: dispatch round-robins blocks across the 8 XCDs by
// blockIdx%8, so give XCD j a CONTIGUOUS band of 128 rows (= 2 whole images).
// All y+/-1 halo reads then hit the same XCD's L2. Perf heuristic only.
__device__ __forceinline__ int row_swizzle(int bid){
    return ((bid & 7) << 7) | (bid >> 3);
}

// ---------------- general cell ----------------
// x = class_h bank raw-viewed as (16,64,64,48) + recurrent gen_h (12ch).
// Bank slot ids[t-1] is stale (last class step wrote htmp_prev instead):
// blocks with b>>2==ids[t-1] read htmp_prev (slot-flat layout == bank-slot
// flat layout) and write their own row through to bank (block-uniform).
__global__ __launch_bounds__(256) void gen_kernel(
    short* __restrict__ bank,          // (PIX*48) bf16 flat
    const short* __restrict__ hin,     // (PIX,12) bf16
    short* __restrict__ hout,          // (PIX,12) bf16
    float* __restrict__ cstate,        // (PIX,12) f32, in-place
    const short* __restrict__ htmp_prev,
    const int* __restrict__ ids, int t,
    const bf16x8* __restrict__ wgt,
    const float* __restrict__ bias)
{
    __shared__ __align__(16) short halo[HALO_SHORTS];
    const int tid = threadIdx.x;
    const int rb  = row_swizzle(blockIdx.x);
    const int p0  = rb << 6;
    const int b   = p0 >> 12;
    const int y   = (p0 >> 6) & 63;

    const int cprev = (t > 0) ? ids[t-1] : -1;
    const bool slotmatch = (cprev >= 0) && ((b >> 2) == cprev);
    const short* bsrc = slotmatch ? htmp_prev : bank;

    for (int tk = tid; tk < 1584; tk += 256){
        int rc = tk >> 3, q8 = tk & 7;
        int r  = rc / 66, c = rc - r * 66;
        int yy = y + r - 1, xx = c - 1;
        bool valid = (yy >= 0) & (yy < 64) & (xx >= 0) & (xx < 64);
        int p  = (b << 12) + (yy << 6) + xx;
        int pb = slotmatch ? (p & 16383) : p;
        union { bf16x8 v; uint2 u2[2]; uint4 u4; } ch;
        ch.u4 = make_uint4(0u, 0u, 0u, 0u);
        if (valid){
            if (q8 < 6){
                ch.u4 = *(const uint4*)(bsrc + pb*48 + q8*8);
                if (slotmatch && r == 1)            // own row: refresh bank
                    *(uint4*)(bank + p*48 + q8*8) = ch.u4;
            } else if (q8 == 6){
                ch.u2[0] = *(const uint2*)(hin + p*12);
                ch.u2[1] = *(const uint2*)(hin + p*12 + 4);
            } else {
                ch.u2[0] = *(const uint2*)(hin + p*12 + 8);
            }
        }
        *(bf16x8*)&halo[(q8*198 + rc)*8] = ch.v;
    }
    __syncthreads();

    const int lane = tid & 63;
    const int w    = tid >> 6;
    const int m    = lane & 15;
    const int quad = lane >> 4;
    const int colbase = 16*w + m;

    f32x4 acc0 = {0.f,0.f,0.f,0.f};
    f32x4 acc1 = acc0, acc2 = acc0;
    #pragma unroll
    for (int ky = 0; ky < 3; ++ky){
        #pragma unroll
        for (int kx = 0; kx < 3; ++kx){
            const int tap = ky*3 + kx;
            #pragma unroll
            for (int kb = 0; kb < 2; ++kb){
                const bf16x8 a = *(const bf16x8*)
                    &halo[(((kb*4 + quad)*198) + ky*66 + colbase + kx)*8];
                const bf16x8* wp = wgt + ((tap*2 + kb)*3)*64 + lane;
                acc0 = __builtin_amdgcn_mfma_f32_16x16x32_bf16(a, wp[0],   acc0, 0,0,0);
                acc1 = __builtin_amdgcn_mfma_f32_16x16x32_bf16(a, wp[64],  acc1, 0,0,0);
                acc2 = __builtin_amdgcn_mfma_f32_16x16x32_bf16(a, wp[128], acc2, 0,0,0);
            }
        }
    }

    __syncthreads();
    float* zw = ((float*)halo) + w * 768;
    #pragma unroll
    for (int r = 0; r < 4; ++r){
        zw[(quad*4 + r)*48 +      m] = acc0[r];
        zw[(quad*4 + r)*48 + 16 + m] = acc1[r];
        zw[(quad*4 + r)*48 + 32 + m] = acc2[r];
    }
    __syncthreads();
    const int pbase = p0 + 16*w;
    #pragma unroll
    for (int s = 0; s < 3; ++s){
        int idx = lane*3 + s;
        int px  = idx / 12;
        int j   = idx - px*12;
        float zi = zw[px*48 +      j] + bias[j];
        float zf = zw[px*48 + 12 + j] + bias[12 + j];
        float zg = zw[px*48 + 24 + j] + bias[24 + j];
        float zo = zw[px*48 + 36 + j] + bias[36 + j];
        int off = pbase*12 + idx;
        float cold = cstate[off];
        float cn = hsig(zf)*cold + hsig(zi)*tanhf(zg);
        cstate[off] = cn;
        hout[off] = f2bf(hsig(zo)*tanhf(cn));
    }
}

// ---------------- class cell ----------------
// aug = concat(frame(12), gen_h(12)) + recurrent class_h[cid](12).
// Writes h_new to htmp (slot shadow) and accumulates out. No scatter kernel.
__global__ __launch_bounds__(256) void class_kernel(
    const short* __restrict__ xbf,     // (BS,NT,HW,12) bf16
    const int*   __restrict__ ids, int t,
    const short* __restrict__ ghn,     // (PIX,12) bf16 (fresh gen_h)
    const short* __restrict__ bank,    // (NCLS,PIX,12) bf16 (slot cid fresh)
    float* __restrict__ class_c,       // (NCLS,PIX,12) f32
    const bf16x8* __restrict__ wgt,
    const float* __restrict__ bias,
    short* __restrict__ htmp,          // (PIX,12) bf16
    float* __restrict__ out)           // (PIX,12) f32, accumulated
{
    __shared__ __align__(16) short halo[HALO_SHORTS];
    const int tid = threadIdx.x;
    const int rb  = row_swizzle(blockIdx.x);
    const int p0  = rb << 6;
    const int b   = p0 >> 12;
    const int y   = (p0 >> 6) & 63;
    const int cid = ids[t];
    const short* chs   = bank + (size_t)cid * STATE;
    const short* frame = xbf + (size_t)(b*NT + t) * (HW*12);

    for (int tk = tid; tk < 1584; tk += 256){
        int rc = tk >> 3, q8 = tk & 7;
        int r  = rc / 66, c = rc - r * 66;
        int yy = y + r - 1, xx = c - 1;
        bool valid = (yy >= 0) & (yy < 64) & (xx >= 0) & (xx < 64);
        int pl = (yy << 6) + xx;
        int p  = (b << 12) + pl;
        union { bf16x8 v; uint2 u2[2]; uint4 u4; } ch;
        ch.u4 = make_uint4(0u, 0u, 0u, 0u);
        if (valid){
            if (q8 == 0){                      // frame ch 0..7
                ch.u2[0] = *(const uint2*)(frame + pl*12);
                ch.u2[1] = *(const uint2*)(frame + pl*12 + 4);
            } else if (q8 == 1){               // frame 8..11 | gen_h 0..3
                ch.u2[0] = *(const uint2*)(frame + pl*12 + 8);
                ch.u2[1] = *(const uint2*)(ghn + p*12);
            } else if (q8 == 2){               // gen_h 4..11
                ch.u2[0] = *(const uint2*)(ghn + p*12 + 4);
                ch.u2[1] = *(const uint2*)(ghn + p*12 + 8);
            } else if (q8 == 3){               // class_h 0..7
                ch.u2[0] = *(const uint2*)(chs + p*12);
                ch.u2[1] = *(const uint2*)(chs + p*12 + 4);
            } else if (q8 == 4){               // class_h 8..11 + pad
                ch.u2[0] = *(const uint2*)(chs + p*12 + 8);
            }
        }
        *(bf16x8*)&halo[(q8*198 + rc)*8] = ch.v;
    }
    __syncthreads();

    const int lane = tid & 63;
    const int w    = tid >> 6;
    const int m    = lane & 15;
    const int quad = lane >> 4;
    const int colbase = 16*w + m;

    f32x4 acc0 = {0.f,0.f,0.f,0.f};
    f32x4 acc1 = acc0, acc2 = acc0;
    #pragma unroll
    for (int ky = 0; ky < 3; ++ky){
        #pragma unroll
        for (int kx = 0; kx < 3; ++kx){
            const int tap = ky*3 + kx;
            #pragma unroll
            for (int kb = 0; kb < 2; ++kb){
                const bf16x8 a = *(const bf16x8*)
                    &halo[(((kb*4 + quad)*198) + ky*66 + colbase + kx)*8];
                const bf16x8* wp = wgt + ((tap*2 + kb)*3)*64 + lane;
                acc0 = __builtin_amdgcn_mfma_f32_16x16x32_bf16(a, wp[0],   acc0, 0,0,0);
                acc1 = __builtin_amdgcn_mfma_f32_16x16x32_bf16(a, wp[64],  acc1, 0,0,0);
                acc2 = __builtin_amdgcn_mfma_f32_16x16x32_bf16(a, wp[128], acc2, 0,0,0);
            }
        }
    }

    __syncthreads();
    float* zw = ((float*)halo) + w * 768;
    #pragma unroll
    for (int r = 0; r < 4; ++r){
        zw[(quad*4 + r)*48 +      m] = acc0[r];
        zw[(quad*4 + r)*48 + 16 + m] = acc1[r];
        zw[(quad*4 + r)*48 + 32 + m] = acc2[r];
    }
    __syncthreads();
    float* cc = class_c + (size_t)cid * STATE;
    const int pbase = p0 + 16*w;
    #pragma unroll
    for (int s = 0; s < 3; ++s){
        int idx = lane*3 + s;
        int px  = idx / 12;
        int j   = idx - px*12;
        float zi = zw[px*48 +      j] + bias[j];
        float zf = zw[px*48 + 12 + j] + bias[12 + j];
        float zg = zw[px*48 + 24 + j] + bias[24 + j];
        float zo = zw[px*48 + 36 + j] + bias[36 + j];
        int off = pbase*12 + idx;
        float cold = cc[off];
        float cn = hsig(zf)*cold + hsig(zi)*tanhf(zg);
        cc[off] = cn;
        float h = hsig(zo)*tanhf(cn);
        htmp[off] = f2bf(h);
        out[off] += h;              // time-sum in fp32 (pre-rounding h)
    }
}

extern "C" void kernel_launch(void* const* d_in, const int* in_sizes, int n_in,
                              void* d_out, int out_size, void* d_ws, size_t ws_size,
                              hipStream_t stream)
{
    (void)in_sizes; (void)n_in; (void)out_size; (void)ws_size;
    const float* x    = (const float*)d_in[0];
    const int*   ids  = (const int*)  d_in[1];
    const float* Wxg  = (const float*)d_in[2];
    const float* Whg  = (const float*)d_in[3];
    const float* bg   = (const float*)d_in[4];
    const float* Wxc  = (const float*)d_in[5];
    const float* Whc  = (const float*)d_in[6];
    const float* bc   = (const float*)d_in[7];
    float* out = (float*)d_out;

    char* base = (char*)d_ws;
    short*  bank    = (short*) (base);               // 6,291,456 B
    float*  class_c = (float*) (base + 6291456);     // 12,582,912
    short*  genh0   = (short*) (base + 18874368);    // 1,572,864
    short*  genh1   = (short*) (base + 20447232);    // 1,572,864
    float*  gen_c   = (float*) (base + 22020096);    // 3,145,728
    short*  htmp0   = (short*) (base + 25165824);    // 1,572,864
    short*  htmp1   = (short*) (base + 26738688);    // 1,572,864
    short*  xbf     = (short*) (base + 28311552);    // 50,331,648
    bf16x8* wgt     = (bf16x8*)(base + 78643200);    // 110,592
    const bf16x8* wgt_gen = wgt;
    const bf16x8* wgt_cls = wgt + 3456;

    hipMemsetAsync(bank,    0, (size_t)2*BANK,  stream);
    hipMemsetAsync(class_c, 0, (size_t)4*BANK,  stream);
    hipMemsetAsync(genh0,   0, (size_t)2*STATE, stream);
    hipMemsetAsync(gen_c,   0, (size_t)4*STATE, stream);
    hipMemsetAsync(out,     0, (size_t)4*STATE, stream);

    repack_kernel<<<27, 256, 0, stream>>>(Wxg, Whg, Wxc, Whc, wgt);
    convert_kernel<<<12288, 256, 0, stream>>>(x, xbf);

    for (int t = 0; t < NT; ++t){
        short* hin       = (t & 1) ? genh1 : genh0;
        short* hnew      = (t & 1) ? genh0 : genh1;
        short* htmp_prev = (t & 1) ? htmp0 : htmp1;
        short* htmp_new  = (t & 1) ? htmp1 : htmp0;
        gen_kernel<<<1024, 256, 0, stream>>>(bank, hin, hnew, gen_c,
                                             htmp_prev, ids, t, wgt_gen, bg);
        class_kernel<<<1024, 256, 0, stream>>>(xbf, ids, t, hnew, bank, class_c,
                                               wgt_cls, bc, htmp_new, out);
    }
}

// Round 6
// 1068.936 us; speedup vs baseline: 6.9890x; 1.1536x over previous
//
#include <hip/hip_runtime.h>
#include <hip/hip_bf16.h>

// ---- problem dims (fixed) ----
#define NCLS 4
#define BS   16
#define NT   32
#define OC   12
#define HW   4096
#define PIX  65536
#define STATE 786432        // PIX*OC
#define BANK  3145728       // NCLS*STATE

typedef short bf16x8 __attribute__((ext_vector_type(8)));
typedef float f32x4  __attribute__((ext_vector_type(4)));

// jax.nn.hard_sigmoid = relu6(x+3)/6
__device__ __forceinline__ float hsig(float v){
    return fminf(fmaxf((v + 3.0f) * (1.0f/6.0f), 0.0f), 1.0f);
}
__device__ __forceinline__ short f2bf(float f){
    union { __hip_bfloat16 h; short s; } u;
    u.h = __float2bfloat16(f);   // RNE
    return u.s;
}

// =====================================================================
// Weight repack (verified R2): fragment-order bf16.
// wgt[cell][tap][kb][nt][lane], elem j = B[k=kb*32+(lane>>4)*8+j][n=nt*16+(lane&15)]
// =====================================================================
__global__ __launch_bounds__(256) void repack_kernel(
    const float* __restrict__ Wxg, const float* __restrict__ Whg,
    const float* __restrict__ Wxc, const float* __restrict__ Whc,
    bf16x8* __restrict__ wgt)
{
    int id = blockIdx.x * 256 + threadIdx.x;    // < 6912
    if (id >= 6912) return;
    int cell = id / 3456;
    int rem  = id - cell * 3456;
    int tap  = rem / 384;  rem -= tap * 384;
    int kb   = rem / 192;  rem -= kb * 192;
    int nt   = rem / 64;
    int lane = rem - nt * 64;
    int quad = lane >> 4;
    int n    = nt * 16 + (lane & 15);
    union { bf16x8 v; short s[8]; } o;
    #pragma unroll
    for (int j = 0; j < 8; ++j){
        int k = kb * 32 + quad * 8 + j;
        float f = 0.0f;
        if (cell == 0){
            if (k < 48)      f = Wxg[(tap*48 + k)*48 + n];
            else if (k < 60) f = Whg[(tap*12 + (k-48))*48 + n];
        } else {
            if (k < 24)      f = Wxc[(tap*24 + k)*48 + n];
            else if (k < 36) f = Whc[(tap*12 + (k-24))*48 + n];
        }
        o.s[j] = f2bf(f);
    }
    wgt[id] = o.v;
}

// LDS halo: plane-major  halo[q8][r][c][8ch] bf16, r in [0,3), c in [0,66)
#define HALO_SHORTS (8*198*8)     // 25344 B

// XCD-aware row swizzle: dispatch round-robins blocks across the 8 XCDs by
// blockIdx%8, so give XCD j a CONTIGUOUS band of 128 rows (= 2 whole images).
__device__ __forceinline__ int row_swizzle(int bid){
    return ((bid & 7) << 7) | (bid >> 3);
}

// ---------------- general cell ----------------
// Staging: thread i<198 owns halo pixel i (r=i/66, c=i%66); issues all its
// chunk loads back-to-back (one latency exposure), then 8 ds_write_b128.
__global__ __launch_bounds__(256) void gen_kernel(
    short* __restrict__ bank,          // (PIX*48) bf16 flat
    const short* __restrict__ hin,     // (PIX,12) bf16
    short* __restrict__ hout,          // (PIX,12) bf16
    float* __restrict__ cstate,        // (PIX,12) f32, in-place
    const short* __restrict__ htmp_prev,
    const int* __restrict__ ids, int t,
    const bf16x8* __restrict__ wgt,
    const float* __restrict__ bias)
{
    __shared__ __align__(16) short halo[HALO_SHORTS];
    const int tid = threadIdx.x;
    const int rb  = row_swizzle(blockIdx.x);
    const int p0  = rb << 6;
    const int b   = p0 >> 12;
    const int y   = (p0 >> 6) & 63;

    const int cprev = (t > 0) ? ids[t-1] : -1;
    const bool slotmatch = (cprev >= 0) && ((b >> 2) == cprev);
    const short* bsrc = slotmatch ? htmp_prev : bank;

    {
        const int i = tid;
        const bool active = (i < 198);
        int r  = i / 66, c = i - r * 66;
        int yy = y + r - 1, xx = c - 1;
        bool valid = active & (yy >= 0) & (yy < 64) & (xx >= 0) & (xx < 64);
        int p  = (b << 12) + (yy << 6) + xx;
        int pb = slotmatch ? (p & 16383) : p;
        uint4 bk[6]; uint2 h0, h1, h2;
        #pragma unroll
        for (int q = 0; q < 6; ++q) bk[q] = make_uint4(0u,0u,0u,0u);
        h0 = make_uint2(0u,0u); h1 = h0; h2 = h0;
        if (valid){
            const short* bp = bsrc + pb*48;
            #pragma unroll
            for (int q = 0; q < 6; ++q) bk[q] = *(const uint4*)(bp + q*8);
            h0 = *(const uint2*)(hin + p*12);
            h1 = *(const uint2*)(hin + p*12 + 4);
            h2 = *(const uint2*)(hin + p*12 + 8);
            if (slotmatch && r == 1){          // own row: refresh bank
                #pragma unroll
                for (int q = 0; q < 6; ++q)
                    *(uint4*)(bank + p*48 + q*8) = bk[q];
            }
        }
        if (active){
            #pragma unroll
            for (int q = 0; q < 6; ++q)
                *(uint4*)&halo[(q*198 + i)*8] = bk[q];
            union { uint2 u2[2]; uint4 u4; } p6, p7;
            p6.u2[0] = h0; p6.u2[1] = h1;
            p7.u2[0] = h2; p7.u2[1] = make_uint2(0u,0u);
            *(uint4*)&halo[(6*198 + i)*8] = p6.u4;
            *(uint4*)&halo[(7*198 + i)*8] = p7.u4;
        }
    }
    __syncthreads();

    const int lane = tid & 63;
    const int w    = tid >> 6;
    const int m    = lane & 15;
    const int quad = lane >> 4;
    const int colbase = 16*w + m;

    f32x4 acc0 = {0.f,0.f,0.f,0.f};
    f32x4 acc1 = acc0, acc2 = acc0;
    #pragma unroll
    for (int ky = 0; ky < 3; ++ky){
        #pragma unroll
        for (int kx = 0; kx < 3; ++kx){
            const int tap = ky*3 + kx;
            #pragma unroll
            for (int kb = 0; kb < 2; ++kb){
                const bf16x8 a = *(const bf16x8*)
                    &halo[(((kb*4 + quad)*198) + ky*66 + colbase + kx)*8];
                const bf16x8* wp = wgt + ((tap*2 + kb)*3)*64 + lane;
                acc0 = __builtin_amdgcn_mfma_f32_16x16x32_bf16(a, wp[0],   acc0, 0,0,0);
                acc1 = __builtin_amdgcn_mfma_f32_16x16x32_bf16(a, wp[64],  acc1, 0,0,0);
                acc2 = __builtin_amdgcn_mfma_f32_16x16x32_bf16(a, wp[128], acc2, 0,0,0);
            }
        }
    }

    __syncthreads();
    float* zw = ((float*)halo) + w * 768;
    #pragma unroll
    for (int r = 0; r < 4; ++r){
        zw[(quad*4 + r)*48 +      m] = acc0[r];
        zw[(quad*4 + r)*48 + 16 + m] = acc1[r];
        zw[(quad*4 + r)*48 + 32 + m] = acc2[r];
    }
    __syncthreads();
    const int pbase = p0 + 16*w;
    #pragma unroll
    for (int s = 0; s < 3; ++s){
        int idx = lane*3 + s;
        int px  = idx / 12;
        int j   = idx - px*12;
        float zi = zw[px*48 +      j] + bias[j];
        float zf = zw[px*48 + 12 + j] + bias[12 + j];
        float zg = zw[px*48 + 24 + j] + bias[24 + j];
        float zo = zw[px*48 + 36 + j] + bias[36 + j];
        int off = pbase*12 + idx;
        float cold = cstate[off];
        float cn = hsig(zf)*cold + hsig(zi)*tanhf(zg);
        cstate[off] = cn;
        hout[off] = f2bf(hsig(zo)*tanhf(cn));
    }
}

// ---------------- class cell ----------------
// aug = concat(frame(12) from fp32 x, gen_h(12)) + recurrent class_h[cid](12).
// Writes h_new to htmp (slot shadow) and accumulates out.
__global__ __launch_bounds__(256) void class_kernel(
    const float* __restrict__ xall,    // (BS,NT,HW,12) f32
    const int*   __restrict__ ids, int t,
    const short* __restrict__ ghn,     // (PIX,12) bf16 (fresh gen_h)
    const short* __restrict__ bank,    // (NCLS,PIX,12) bf16 (slot cid fresh)
    float* __restrict__ class_c,       // (NCLS,PIX,12) f32
    const bf16x8* __restrict__ wgt,
    const float* __restrict__ bias,
    short* __restrict__ htmp,          // (PIX,12) bf16
    float* __restrict__ out)           // (PIX,12) f32, accumulated
{
    __shared__ __align__(16) short halo[HALO_SHORTS];
    const int tid = threadIdx.x;
    const int rb  = row_swizzle(blockIdx.x);
    const int p0  = rb << 6;
    const int b   = p0 >> 12;
    const int y   = (p0 >> 6) & 63;
    const int cid = ids[t];
    const short* chs   = bank + (size_t)cid * STATE;
    const float* frame = xall + (size_t)(b*NT + t) * (HW*12);

    {
        const int i = tid;
        const bool active = (i < 198);
        int r  = i / 66, c = i - r * 66;
        int yy = y + r - 1, xx = c - 1;
        bool valid = active & (yy >= 0) & (yy < 64) & (xx >= 0) & (xx < 64);
        int pl = (yy << 6) + xx;
        int p  = (b << 12) + pl;
        float4 f0, f1, f2;
        f0 = make_float4(0.f,0.f,0.f,0.f); f1 = f0; f2 = f0;
        uint2 g0, g1, g2, s0, s1, s2;
        g0 = make_uint2(0u,0u); g1 = g0; g2 = g0; s0 = g0; s1 = g0; s2 = g0;
        if (valid){
            f0 = *(const float4*)(frame + pl*12);
            f1 = *(const float4*)(frame + pl*12 + 4);
            f2 = *(const float4*)(frame + pl*12 + 8);
            g0 = *(const uint2*)(ghn + p*12);
            g1 = *(const uint2*)(ghn + p*12 + 4);
            g2 = *(const uint2*)(ghn + p*12 + 8);
            s0 = *(const uint2*)(chs + p*12);
            s1 = *(const uint2*)(chs + p*12 + 4);
            s2 = *(const uint2*)(chs + p*12 + 8);
        }
        if (active){
            union { uint4 u4; uint2 u2[2]; short s[8]; } pk;
            // q8=0: frame ch 0..7
            pk.s[0]=f2bf(f0.x); pk.s[1]=f2bf(f0.y); pk.s[2]=f2bf(f0.z); pk.s[3]=f2bf(f0.w);
            pk.s[4]=f2bf(f1.x); pk.s[5]=f2bf(f1.y); pk.s[6]=f2bf(f1.z); pk.s[7]=f2bf(f1.w);
            *(uint4*)&halo[(0*198 + i)*8] = pk.u4;
            // q8=1: frame 8..11 | gen_h 0..3
            pk.s[0]=f2bf(f2.x); pk.s[1]=f2bf(f2.y); pk.s[2]=f2bf(f2.z); pk.s[3]=f2bf(f2.w);
            pk.u2[1] = g0;
            *(uint4*)&halo[(1*198 + i)*8] = pk.u4;
            // q8=2: gen_h 4..11
            pk.u2[0] = g1; pk.u2[1] = g2;
            *(uint4*)&halo[(2*198 + i)*8] = pk.u4;
            // q8=3: class_h 0..7
            pk.u2[0] = s0; pk.u2[1] = s1;
            *(uint4*)&halo[(3*198 + i)*8] = pk.u4;
            // q8=4: class_h 8..11 + pad
            pk.u2[0] = s2; pk.u2[1] = make_uint2(0u,0u);
            *(uint4*)&halo[(4*198 + i)*8] = pk.u4;
            // q8=5..7: zeros
            uint4 z = make_uint4(0u,0u,0u,0u);
            *(uint4*)&halo[(5*198 + i)*8] = z;
            *(uint4*)&halo[(6*198 + i)*8] = z;
            *(uint4*)&halo[(7*198 + i)*8] = z;
        }
    }
    __syncthreads();

    const int lane = tid & 63;
    const int w    = tid >> 6;
    const int m    = lane & 15;
    const int quad = lane >> 4;
    const int colbase = 16*w + m;

    f32x4 acc0 = {0.f,0.f,0.f,0.f};
    f32x4 acc1 = acc0, acc2 = acc0;
    #pragma unroll
    for (int ky = 0; ky < 3; ++ky){
        #pragma unroll
        for (int kx = 0; kx < 3; ++kx){
            const int tap = ky*3 + kx;
            #pragma unroll
            for (int kb = 0; kb < 2; ++kb){
                const bf16x8 a = *(const bf16x8*)
                    &halo[(((kb*4 + quad)*198) + ky*66 + colbase + kx)*8];
                const bf16x8* wp = wgt + ((tap*2 + kb)*3)*64 + lane;
                acc0 = __builtin_amdgcn_mfma_f32_16x16x32_bf16(a, wp[0],   acc0, 0,0,0);
                acc1 = __builtin_amdgcn_mfma_f32_16x16x32_bf16(a, wp[64],  acc1, 0,0,0);
                acc2 = __builtin_amdgcn_mfma_f32_16x16x32_bf16(a, wp[128], acc2, 0,0,0);
            }
        }
    }

    __syncthreads();
    float* zw = ((float*)halo) + w * 768;
    #pragma unroll
    for (int r = 0; r < 4; ++r){
        zw[(quad*4 + r)*48 +      m] = acc0[r];
        zw[(quad*4 + r)*48 + 16 + m] = acc1[r];
        zw[(quad*4 + r)*48 + 32 + m] = acc2[r];
    }
    __syncthreads();
    float* cc = class_c + (size_t)cid * STATE;
    const int pbase = p0 + 16*w;
    #pragma unroll
    for (int s = 0; s < 3; ++s){
        int idx = lane*3 + s;
        int px  = idx / 12;
        int j   = idx - px*12;
        float zi = zw[px*48 +      j] + bias[j];
        float zf = zw[px*48 + 12 + j] + bias[12 + j];
        float zg = zw[px*48 + 24 + j] + bias[24 + j];
        float zo = zw[px*48 + 36 + j] + bias[36 + j];
        int off = pbase*12 + idx;
        float cold = cc[off];
        float cn = hsig(zf)*cold + hsig(zi)*tanhf(zg);
        cc[off] = cn;
        float h = hsig(zo)*tanhf(cn);
        htmp[off] = f2bf(h);
        out[off] += h;              // time-sum in fp32 (pre-rounding h)
    }
}

extern "C" void kernel_launch(void* const* d_in, const int* in_sizes, int n_in,
                              void* d_out, int out_size, void* d_ws, size_t ws_size,
                              hipStream_t stream)
{
    (void)in_sizes; (void)n_in; (void)out_size; (void)ws_size;
    const float* x    = (const float*)d_in[0];
    const int*   ids  = (const int*)  d_in[1];
    const float* Wxg  = (const float*)d_in[2];
    const float* Whg  = (const float*)d_in[3];
    const float* bg   = (const float*)d_in[4];
    const float* Wxc  = (const float*)d_in[5];
    const float* Whc  = (const float*)d_in[6];
    const float* bc   = (const float*)d_in[7];
    float* out = (float*)d_out;

    char* base = (char*)d_ws;
    short*  bank    = (short*) (base);               // 6,291,456 B
    float*  class_c = (float*) (base + 6291456);     // 12,582,912
    short*  genh0   = (short*) (base + 18874368);    // 1,572,864
    short*  genh1   = (short*) (base + 20447232);    // 1,572,864
    float*  gen_c   = (float*) (base + 22020096);    // 3,145,728
    short*  htmp0   = (short*) (base + 25165824);    // 1,572,864
    short*  htmp1   = (short*) (base + 26738688);    // 1,572,864
    bf16x8* wgt     = (bf16x8*)(base + 28311552);    // 110,592
    const bf16x8* wgt_gen = wgt;
    const bf16x8* wgt_cls = wgt + 3456;

    hipMemsetAsync(bank,    0, (size_t)2*BANK,  stream);
    hipMemsetAsync(class_c, 0, (size_t)4*BANK,  stream);
    hipMemsetAsync(genh0,   0, (size_t)2*STATE, stream);
    hipMemsetAsync(gen_c,   0, (size_t)4*STATE, stream);
    hipMemsetAsync(out,     0, (size_t)4*STATE, stream);

    repack_kernel<<<27, 256, 0, stream>>>(Wxg, Whg, Wxc, Whc, wgt);

    for (int t = 0; t < NT; ++t){
        short* hin       = (t & 1) ? genh1 : genh0;
        short* hnew      = (t & 1) ? genh0 : genh1;
        short* htmp_prev = (t & 1) ? htmp0 : htmp1;
        short* htmp_new  = (t & 1) ? htmp1 : htmp0;
        gen_kernel<<<1024, 256, 0, stream>>>(bank, hin, hnew, gen_c,
                                             htmp_prev, ids, t, wgt_gen, bg);
        class_kernel<<<1024, 256, 0, stream>>>(x, ids, t, hnew, bank, class_c,
                                               wgt_cls, bc, htmp_new, out);
    }
}

// Round 7
// 1062.312 us; speedup vs baseline: 7.0326x; 1.0062x over previous
//
#include <hip/hip_runtime.h>
#include <hip/hip_bf16.h>

// ---- problem dims (fixed) ----
#define NCLS 4
#define BS   16
#define NT   32
#define OC   12
#define HW   4096
#define PIX  65536
#define STATE 786432        // PIX*OC
#define BANK  3145728       // NCLS*STATE

typedef short bf16x8 __attribute__((ext_vector_type(8)));
typedef float f32x4  __attribute__((ext_vector_type(4)));

// jax.nn.hard_sigmoid = relu6(x+3)/6
__device__ __forceinline__ float hsig(float v){
    return fminf(fmaxf((v + 3.0f) * (1.0f/6.0f), 0.0f), 1.0f);
}
__device__ __forceinline__ short f2bf(float f){
    union { __hip_bfloat16 h; short s; } u;
    u.h = __float2bfloat16(f);   // RNE
    return u.s;
}

// =====================================================================
// Weight repack (verified R2): fragment-order bf16.
// wgt[cell][tap][kb][nt][lane], elem j = B[k=kb*32+(lane>>4)*8+j][n=nt*16+(lane&15)]
// =====================================================================
__global__ __launch_bounds__(256) void repack_kernel(
    const float* __restrict__ Wxg, const float* __restrict__ Whg,
    const float* __restrict__ Wxc, const float* __restrict__ Whc,
    bf16x8* __restrict__ wgt)
{
    int id = blockIdx.x * 256 + threadIdx.x;    // < 6912
    if (id >= 6912) return;
    int cell = id / 3456;
    int rem  = id - cell * 3456;
    int tap  = rem / 384;  rem -= tap * 384;
    int kb   = rem / 192;  rem -= kb * 192;
    int nt   = rem / 64;
    int lane = rem - nt * 64;
    int quad = lane >> 4;
    int n    = nt * 16 + (lane & 15);
    union { bf16x8 v; short s[8]; } o;
    #pragma unroll
    for (int j = 0; j < 8; ++j){
        int k = kb * 32 + quad * 8 + j;
        float f = 0.0f;
        if (cell == 0){
            if (k < 48)      f = Wxg[(tap*48 + k)*48 + n];
            else if (k < 60) f = Whg[(tap*12 + (k-48))*48 + n];
        } else {
            if (k < 24)      f = Wxc[(tap*24 + k)*48 + n];
            else if (k < 36) f = Whc[(tap*12 + (k-24))*48 + n];
        }
        o.s[j] = f2bf(f);
    }
    wgt[id] = o.v;
}

// LDS halo: 4 k-planes (one kb half at a time): halo[q][r][c][8ch] bf16,
// q in [0,4), r in [0,3), c in [0,66). 12672 B -> 5 blocks/CU at 64K limit.
#define HALO_SHORTS (4*198*8)     // 6336 shorts = 12672 B

// XCD-aware row swizzle: XCD j gets a CONTIGUOUS band of 128 rows (2 images).
__device__ __forceinline__ int row_swizzle(int bid){
    return ((bid & 7) << 7) | (bid >> 3);
}

// ---------------- general cell ----------------
// All global loads issued up-front (one latency exposure); halo planes
// written in two kb-phases through the same 4-plane LDS buffer.
__global__ __launch_bounds__(256, 4) void gen_kernel(
    short* __restrict__ bank,          // (PIX*48) bf16 flat
    const short* __restrict__ hin,     // (PIX,12) bf16
    short* __restrict__ hout,          // (PIX,12) bf16
    float* __restrict__ cstate,        // (PIX,12) f32, in-place
    const short* __restrict__ htmp_prev,
    const int* __restrict__ ids, int t,
    const bf16x8* __restrict__ wgt,
    const float* __restrict__ bias)
{
    __shared__ __align__(16) short halo[HALO_SHORTS];
    const int tid = threadIdx.x;
    const int rb  = row_swizzle(blockIdx.x);
    const int p0  = rb << 6;
    const int b   = p0 >> 12;
    const int y   = (p0 >> 6) & 63;

    const int cprev = (t > 0) ? ids[t-1] : -1;
    const bool slotmatch = (cprev >= 0) && ((b >> 2) == cprev);
    const short* bsrc = slotmatch ? htmp_prev : bank;

    // ---- issue all staging loads up-front ----
    const int i = tid;
    const bool active = (i < 198);
    {
        int r  = i / 66, c = i - r * 66;
        int yy = y + r - 1, xx = c - 1;
        bool valid = active & (yy >= 0) & (yy < 64) & (xx >= 0) & (xx < 64);
        int p  = (b << 12) + (yy << 6) + xx;
        int pb = slotmatch ? (p & 16383) : p;
        uint4 bk[6]; uint2 h0, h1, h2;
        #pragma unroll
        for (int q = 0; q < 6; ++q) bk[q] = make_uint4(0u,0u,0u,0u);
        h0 = make_uint2(0u,0u); h1 = h0; h2 = h0;
        if (valid){
            const short* bp = bsrc + pb*48;
            #pragma unroll
            for (int q = 0; q < 6; ++q) bk[q] = *(const uint4*)(bp + q*8);
            h0 = *(const uint2*)(hin + p*12);
            h1 = *(const uint2*)(hin + p*12 + 4);
            h2 = *(const uint2*)(hin + p*12 + 8);
            if (slotmatch && r == 1){          // own row: refresh bank
                #pragma unroll
                for (int q = 0; q < 6; ++q)
                    *(uint4*)(bank + p*48 + q*8) = bk[q];
            }
        }
        // ---- kb=0 planes: bank ch 0..31 ----
        if (active){
            #pragma unroll
            for (int q = 0; q < 4; ++q)
                *(uint4*)&halo[(q*198 + i)*8] = bk[q];
        }
        __syncthreads();

        // save kb=1 payload in a place that survives the mfma0 block below
        // (registers bk[4],bk[5],h0..h2 stay live)
        const int lane = tid & 63;
        const int w    = tid >> 6;
        const int m    = lane & 15;
        const int quad = lane >> 4;
        const int colbase = 16*w + m;

        f32x4 acc0 = {0.f,0.f,0.f,0.f};
        f32x4 acc1 = acc0, acc2 = acc0;

        // ---- MFMA kb=0 ----
        #pragma unroll
        for (int ky = 0; ky < 3; ++ky){
            #pragma unroll
            for (int kx = 0; kx < 3; ++kx){
                const int tap = ky*3 + kx;
                const bf16x8 a = *(const bf16x8*)
                    &halo[((quad*198) + ky*66 + colbase + kx)*8];
                const bf16x8* wp = wgt + ((tap*2 + 0)*3)*64 + lane;
                acc0 = __builtin_amdgcn_mfma_f32_16x16x32_bf16(a, wp[0],   acc0, 0,0,0);
                acc1 = __builtin_amdgcn_mfma_f32_16x16x32_bf16(a, wp[64],  acc1, 0,0,0);
                acc2 = __builtin_amdgcn_mfma_f32_16x16x32_bf16(a, wp[128], acc2, 0,0,0);
            }
        }
        __syncthreads();

        // ---- kb=1 planes: bank ch 32..47, h 0..11 ----
        if (active){
            *(uint4*)&halo[(0*198 + i)*8] = bk[4];
            *(uint4*)&halo[(1*198 + i)*8] = bk[5];
            union { uint2 u2[2]; uint4 u4; } p2, p3;
            p2.u2[0] = h0; p2.u2[1] = h1;
            p3.u2[0] = h2; p3.u2[1] = make_uint2(0u,0u);
            *(uint4*)&halo[(2*198 + i)*8] = p2.u4;
            *(uint4*)&halo[(3*198 + i)*8] = p3.u4;
        }
        __syncthreads();

        // ---- MFMA kb=1 ----
        #pragma unroll
        for (int ky = 0; ky < 3; ++ky){
            #pragma unroll
            for (int kx = 0; kx < 3; ++kx){
                const int tap = ky*3 + kx;
                const bf16x8 a = *(const bf16x8*)
                    &halo[((quad*198) + ky*66 + colbase + kx)*8];
                const bf16x8* wp = wgt + ((tap*2 + 1)*3)*64 + lane;
                acc0 = __builtin_amdgcn_mfma_f32_16x16x32_bf16(a, wp[0],   acc0, 0,0,0);
                acc1 = __builtin_amdgcn_mfma_f32_16x16x32_bf16(a, wp[64],  acc1, 0,0,0);
                acc2 = __builtin_amdgcn_mfma_f32_16x16x32_bf16(a, wp[128], acc2, 0,0,0);
            }
        }
        __syncthreads();

        // ---- epilogue: z transpose through LDS + LSTM math ----
        float* zw = ((float*)halo) + w * 768;
        #pragma unroll
        for (int r2 = 0; r2 < 4; ++r2){
            zw[(quad*4 + r2)*48 +      m] = acc0[r2];
            zw[(quad*4 + r2)*48 + 16 + m] = acc1[r2];
            zw[(quad*4 + r2)*48 + 32 + m] = acc2[r2];
        }
        __syncthreads();
        const int pbase = p0 + 16*w;
        #pragma unroll
        for (int s = 0; s < 3; ++s){
            int idx = lane*3 + s;
            int px  = idx / 12;
            int j   = idx - px*12;
            float zi = zw[px*48 +      j] + bias[j];
            float zf = zw[px*48 + 12 + j] + bias[12 + j];
            float zg = zw[px*48 + 24 + j] + bias[24 + j];
            float zo = zw[px*48 + 36 + j] + bias[36 + j];
            int off = pbase*12 + idx;
            float cold = cstate[off];
            float cn = hsig(zf)*cold + hsig(zi)*tanhf(zg);
            cstate[off] = cn;
            hout[off] = f2bf(hsig(zo)*tanhf(cn));
        }
    }
}

// ---------------- class cell ----------------
__global__ __launch_bounds__(256, 4) void class_kernel(
    const float* __restrict__ xall,    // (BS,NT,HW,12) f32
    const int*   __restrict__ ids, int t,
    const short* __restrict__ ghn,     // (PIX,12) bf16 (fresh gen_h)
    const short* __restrict__ bank,    // (NCLS,PIX,12) bf16 (slot cid fresh)
    float* __restrict__ class_c,       // (NCLS,PIX,12) f32
    const bf16x8* __restrict__ wgt,
    const float* __restrict__ bias,
    short* __restrict__ htmp,          // (PIX,12) bf16
    float* __restrict__ out)           // (PIX,12) f32, accumulated
{
    __shared__ __align__(16) short halo[HALO_SHORTS];
    const int tid = threadIdx.x;
    const int rb  = row_swizzle(blockIdx.x);
    const int p0  = rb << 6;
    const int b   = p0 >> 12;
    const int y   = (p0 >> 6) & 63;
    const int cid = ids[t];
    const short* chs   = bank + (size_t)cid * STATE;
    const float* frame = xall + (size_t)(b*NT + t) * (HW*12);

    const int i = tid;
    const bool active = (i < 198);
    {
        int r  = i / 66, c = i - r * 66;
        int yy = y + r - 1, xx = c - 1;
        bool valid = active & (yy >= 0) & (yy < 64) & (xx >= 0) & (xx < 64);
        int pl = (yy << 6) + xx;
        int p  = (b << 12) + pl;
        float4 f0, f1, f2;
        f0 = make_float4(0.f,0.f,0.f,0.f); f1 = f0; f2 = f0;
        uint2 g0, g1, g2, s0, s1, s2;
        g0 = make_uint2(0u,0u); g1 = g0; g2 = g0; s0 = g0; s1 = g0; s2 = g0;
        if (valid){
            f0 = *(const float4*)(frame + pl*12);
            f1 = *(const float4*)(frame + pl*12 + 4);
            f2 = *(const float4*)(frame + pl*12 + 8);
            g0 = *(const uint2*)(ghn + p*12);
            g1 = *(const uint2*)(ghn + p*12 + 4);
            g2 = *(const uint2*)(ghn + p*12 + 8);
            s0 = *(const uint2*)(chs + p*12);
            s1 = *(const uint2*)(chs + p*12 + 4);
            s2 = *(const uint2*)(chs + p*12 + 8);
        }
        // ---- kb=0 planes: frame 0..11 | gen_h 0..11 | class_h 0..7 ----
        if (active){
            union { uint4 u4; uint2 u2[2]; short s[8]; } pk;
            pk.s[0]=f2bf(f0.x); pk.s[1]=f2bf(f0.y); pk.s[2]=f2bf(f0.z); pk.s[3]=f2bf(f0.w);
            pk.s[4]=f2bf(f1.x); pk.s[5]=f2bf(f1.y); pk.s[6]=f2bf(f1.z); pk.s[7]=f2bf(f1.w);
            *(uint4*)&halo[(0*198 + i)*8] = pk.u4;
            pk.s[0]=f2bf(f2.x); pk.s[1]=f2bf(f2.y); pk.s[2]=f2bf(f2.z); pk.s[3]=f2bf(f2.w);
            pk.u2[1] = g0;
            *(uint4*)&halo[(1*198 + i)*8] = pk.u4;
            pk.u2[0] = g1; pk.u2[1] = g2;
            *(uint4*)&halo[(2*198 + i)*8] = pk.u4;
            pk.u2[0] = s0; pk.u2[1] = s1;
            *(uint4*)&halo[(3*198 + i)*8] = pk.u4;
        }
        __syncthreads();

        const int lane = tid & 63;
        const int w    = tid >> 6;
        const int m    = lane & 15;
        const int quad = lane >> 4;
        const int colbase = 16*w + m;

        f32x4 acc0 = {0.f,0.f,0.f,0.f};
        f32x4 acc1 = acc0, acc2 = acc0;

        // ---- MFMA kb=0 ----
        #pragma unroll
        for (int ky = 0; ky < 3; ++ky){
            #pragma unroll
            for (int kx = 0; kx < 3; ++kx){
                const int tap = ky*3 + kx;
                const bf16x8 a = *(const bf16x8*)
                    &halo[((quad*198) + ky*66 + colbase + kx)*8];
                const bf16x8* wp = wgt + ((tap*2 + 0)*3)*64 + lane;
                acc0 = __builtin_amdgcn_mfma_f32_16x16x32_bf16(a, wp[0],   acc0, 0,0,0);
                acc1 = __builtin_amdgcn_mfma_f32_16x16x32_bf16(a, wp[64],  acc1, 0,0,0);
                acc2 = __builtin_amdgcn_mfma_f32_16x16x32_bf16(a, wp[128], acc2, 0,0,0);
            }
        }
        __syncthreads();

        // ---- kb=1 planes: class_h 8..11, rest zero ----
        if (active){
            union { uint4 u4; uint2 u2[2]; } p0k;
            p0k.u2[0] = s2; p0k.u2[1] = make_uint2(0u,0u);
            uint4 z = make_uint4(0u,0u,0u,0u);
            *(uint4*)&halo[(0*198 + i)*8] = p0k.u4;
            *(uint4*)&halo[(1*198 + i)*8] = z;
            *(uint4*)&halo[(2*198 + i)*8] = z;
            *(uint4*)&halo[(3*198 + i)*8] = z;
        }
        __syncthreads();

        // ---- MFMA kb=1 ----
        #pragma unroll
        for (int ky = 0; ky < 3; ++ky){
            #pragma unroll
            for (int kx = 0; kx < 3; ++kx){
                const int tap = ky*3 + kx;
                const bf16x8 a = *(const bf16x8*)
                    &halo[((quad*198) + ky*66 + colbase + kx)*8];
                const bf16x8* wp = wgt + ((tap*2 + 1)*3)*64 + lane;
                acc0 = __builtin_amdgcn_mfma_f32_16x16x32_bf16(a, wp[0],   acc0, 0,0,0);
                acc1 = __builtin_amdgcn_mfma_f32_16x16x32_bf16(a, wp[64],  acc1, 0,0,0);
                acc2 = __builtin_amdgcn_mfma_f32_16x16x32_bf16(a, wp[128], acc2, 0,0,0);
            }
        }
        __syncthreads();

        // ---- epilogue ----
        float* zw = ((float*)halo) + w * 768;
        #pragma unroll
        for (int r2 = 0; r2 < 4; ++r2){
            zw[(quad*4 + r2)*48 +      m] = acc0[r2];
            zw[(quad*4 + r2)*48 + 16 + m] = acc1[r2];
            zw[(quad*4 + r2)*48 + 32 + m] = acc2[r2];
        }
        __syncthreads();
        float* cc = class_c + (size_t)cid * STATE;
        const int pbase = p0 + 16*w;
        #pragma unroll
        for (int s = 0; s < 3; ++s){
            int idx = lane*3 + s;
            int px  = idx / 12;
            int j   = idx - px*12;
            float zi = zw[px*48 +      j] + bias[j];
            float zf = zw[px*48 + 12 + j] + bias[12 + j];
            float zg = zw[px*48 + 24 + j] + bias[24 + j];
            float zo = zw[px*48 + 36 + j] + bias[36 + j];
            int off = pbase*12 + idx;
            float cold = cc[off];
            float cn = hsig(zf)*cold + hsig(zi)*tanhf(zg);
            cc[off] = cn;
            float h = hsig(zo)*tanhf(cn);
            htmp[off] = f2bf(h);
            out[off] += h;              // time-sum in fp32 (pre-rounding h)
        }
    }
}

extern "C" void kernel_launch(void* const* d_in, const int* in_sizes, int n_in,
                              void* d_out, int out_size, void* d_ws, size_t ws_size,
                              hipStream_t stream)
{
    (void)in_sizes; (void)n_in; (void)out_size; (void)ws_size;
    const float* x    = (const float*)d_in[0];
    const int*   ids  = (const int*)  d_in[1];
    const float* Wxg  = (const float*)d_in[2];
    const float* Whg  = (const float*)d_in[3];
    const float* bg   = (const float*)d_in[4];
    const float* Wxc  = (const float*)d_in[5];
    const float* Whc  = (const float*)d_in[6];
    const float* bc   = (const float*)d_in[7];
    float* out = (float*)d_out;

    char* base = (char*)d_ws;
    short*  bank    = (short*) (base);               // 6,291,456 B
    float*  class_c = (float*) (base + 6291456);     // 12,582,912
    short*  genh0   = (short*) (base + 18874368);    // 1,572,864
    short*  genh1   = (short*) (base + 20447232);    // 1,572,864
    float*  gen_c   = (float*) (base + 22020096);    // 3,145,728
    short*  htmp0   = (short*) (base + 25165824);    // 1,572,864
    short*  htmp1   = (short*) (base + 26738688);    // 1,572,864
    bf16x8* wgt     = (bf16x8*)(base + 28311552);    // 110,592
    const bf16x8* wgt_gen = wgt;
    const bf16x8* wgt_cls = wgt + 3456;

    hipMemsetAsync(bank,    0, (size_t)2*BANK,  stream);
    hipMemsetAsync(class_c, 0, (size_t)4*BANK,  stream);
    hipMemsetAsync(genh0,   0, (size_t)2*STATE, stream);
    hipMemsetAsync(gen_c,   0, (size_t)4*STATE, stream);
    hipMemsetAsync(out,     0, (size_t)4*STATE, stream);

    repack_kernel<<<27, 256, 0, stream>>>(Wxg, Whg, Wxc, Whc, wgt);

    for (int t = 0; t < NT; ++t){
        short* hin       = (t & 1) ? genh1 : genh0;
        short* hnew      = (t & 1) ? genh0 : genh1;
        short* htmp_prev = (t & 1) ? htmp0 : htmp1;
        short* htmp_new  = (t & 1) ? htmp1 : htmp0;
        gen_kernel<<<1024, 256, 0, stream>>>(bank, hin, hnew, gen_c,
                                             htmp_prev, ids, t, wgt_gen, bg);
        class_kernel<<<1024, 256, 0, stream>>>(x, ids, t, hnew, bank, class_c,
                                               wgt_cls, bc, htmp_new, out);
    }
}